// Round 2
// baseline (275.872 us; speedup 1.0000x reference)
//
#include <hip/hip_runtime.h>
#include <hip/hip_bf16.h>

#define D_HID 32
#define D_IN 128
#define NEG 0.2f
#define BSH 7          // log2 bucket size
#define BSZ 128        // dst nodes per bucket
#define MAXB 1024      // max buckets (N <= 131072)
#define MAXD 128       // degree-sort bins

typedef unsigned short u16;
typedef __attribute__((ext_vector_type(8))) short short8;   // 8 bf16 (4 VGPRs)
typedef __attribute__((ext_vector_type(4))) float float4v;  // 4 fp32 acc

__device__ __forceinline__ float b2f(u16 u){
  union { unsigned int i; float f; } c; c.i = ((unsigned int)u) << 16; return c.f;
}

__device__ __forceinline__ u16 f2b_rne(float f){
  union { float f; unsigned int u; } c; c.f = f;
  unsigned int u = c.u;
  return (u16)((u + 0x7FFFu + ((u >> 16) & 1u)) >> 16);
}

// fp32 -> bf16 hi + bf16 lo (captures ~16 mantissa bits)
__device__ __forceinline__ void split_bf16(float v, u16& hi, u16& lo){
  hi = f2b_rne(v);
  lo = f2b_rne(v - b2f(hi));
}

__device__ __forceinline__ float ldf(const void* __restrict__ p, int f32, long long i){
  return f32 ? ((const float*)p)[i] : b2f(((const u16*)p)[i]);
}

__device__ __forceinline__ int atomAddI(int* p, int v){
  return __hip_atomic_fetch_add(p, v, __ATOMIC_RELAXED, __HIP_MEMORY_SCOPE_AGENT);
}

// width-8 xor-reduce: 2 DPP quad-perm adds (VALU-rate) + 1 ds_swizzle (lane^4).
// Bit-identical pairing/order to the previous __shfl_xor(1)/(2)/(4) version.
__device__ __forceinline__ float red8(float p){
  p += __int_as_float(__builtin_amdgcn_update_dpp(
         0, __float_as_int(p), 0xB1, 0xF, 0xF, true));   // quad_perm(1,0,3,2) = ^1
  p += __int_as_float(__builtin_amdgcn_update_dpp(
         0, __float_as_int(p), 0x4E, 0xF, 0xF, true));   // quad_perm(2,3,0,1) = ^2
  p += __int_as_float(__builtin_amdgcn_ds_swizzle(
         __float_as_int(p), 0x101F));                    // lane^4
  return p;
}

// per-edge: leaky(xv+xrk)·att over this lane's 4 feats, reduce over 8 lanes, exp
__device__ __forceinline__ float edge_ev(const float4 xv, const float4 xrk,
                                         const float4 attk){
  float hx = xv.x + xrk.x; hx = fmaxf(hx, NEG*hx);
  float hy = xv.y + xrk.y; hy = fmaxf(hy, NEG*hy);
  float hz = xv.z + xrk.z; hz = fmaxf(hz, NEG*hz);
  float hw = xv.w + xrk.w; hw = fmaxf(hw, NEG*hw);
  float p = hx*attk.x;
  p = fmaf(hy, attk.y, p);
  p = fmaf(hz, attk.z, p);
  p = fmaf(hw, attk.w, p);
  p = red8(p);
  p = fminf(p, 60.f);                                    // safety clamp
  return __expf(p);
}

// flags[0]: edge_index is int64-layout. flags[1]: float inputs are fp32.
__global__ void detect_flags(const int* __restrict__ ei, const u16* __restrict__ xw,
                             int* __restrict__ flags){
  __shared__ int insane_s, nz_s;
  int t = threadIdx.x;
  if (t == 0){ insane_s = 0; nz_s = 0; }
  __syncthreads();
  int pred = (t < 64) ? (ei[2*t+1] != 0) : 0;
  int e = (xw[t] >> 7) & 0xFF;
  int bad = (e < 100 || e > 140) ? 1 : 0;
  #pragma unroll
  for (int off = 32; off >= 1; off >>= 1){
    bad  += __shfl_down(bad,  off, 64);
    pred += __shfl_down(pred, off, 64);
  }
  if ((t & 63) == 0){
    atomicAdd(&insane_s, bad);
    atomicAdd(&nz_s, pred);
  }
  __syncthreads();
  if (t == 0){
    flags[0] = (nz_s == 0) ? 1 : 0;
    flags[1] = (insane_s > 16) ? 1 : 0;
  }
}

__device__ __forceinline__ void edge_nodes(const int* __restrict__ ei, int E_, int is64,
                                           int e, int& src, int& dst){
  if (is64){ src = ei[2*e]; dst = ei[2*E_ + 2*e]; }
  else     { src = ei[e];   dst = ei[E_ + e]; }
}

// ---------------- W-fragment precompute (verified r11) ----------------
__global__ void prep_wfrag(const void* __restrict__ Wl, const void* __restrict__ Wr,
                           const int* __restrict__ flags, int K,
                           uint4* __restrict__ whi, uint4* __restrict__ wlo){
  int t = blockIdx.x * blockDim.x + threadIdx.x;
  int KS = K >> 5;
  int total = 4 * KS * 64;
  if (t >= total) return;
  int lane = t & 63;
  int rem = t >> 6;            // ctile*KS + kstep
  int kstep = rem % KS;
  int ctile = rem / KS;
  int f32 = flags[1];
  int col = ctile * 16 + (lane & 15);
  int quad = lane >> 4;
  union { u16 s[8]; uint4 q; } ch, cl;
  #pragma unroll
  for (int j = 0; j < 8; ++j){
    int k = kstep*32 + quad*8 + j;
    float v = (col < 32) ? ldf(Wl, f32, (long long)k*D_HID + col)
                         : ldf(Wr, f32, (long long)k*D_HID + (col - 32));
    u16 hi, lo; split_bf16(v, hi, lo);
    ch.s[j] = hi; cl.s[j] = lo;
  }
  whi[rem*64 + lane] = ch.q;
  wlo[rem*64 + lane] = cl.q;
}

// ---------------- MFMA node transform (split-bf16, verified r11) -----------------
template<int K>
__global__ void mfma_gemm(const void* __restrict__ X,
                          const uint4* __restrict__ whi, const uint4* __restrict__ wlo,
                          const int* __restrict__ flags, int force_f32,
                          float* __restrict__ xl, float* __restrict__ xr, int N_)
{
  constexpr int KS = K >> 5;
  int tile = blockIdx.x * (blockDim.x >> 6) + (threadIdx.x >> 6);
  if (tile * 16 >= N_) return;
  int lane = threadIdx.x & 63;
  int quad = lane >> 4;
  int m = tile*16 + (lane & 15);
  if (m >= N_) m = N_ - 1;             // tail-safe loads (stores guarded)
  int f32 = force_f32 | flags[1];

  float4v acc[4];
  #pragma unroll
  for (int c = 0; c < 4; ++c) acc[c] = (float4v){0.f,0.f,0.f,0.f};

  #pragma unroll
  for (int ks = 0; ks < KS; ++ks){
    long long base = (long long)m * K + ks*32 + quad*8;
    float av[8];
    if (f32){
      const float4* xp = (const float4*)((const float*)X + base);
      float4 t0 = xp[0], t1 = xp[1];
      av[0]=t0.x; av[1]=t0.y; av[2]=t0.z; av[3]=t0.w;
      av[4]=t1.x; av[5]=t1.y; av[6]=t1.z; av[7]=t1.w;
    } else {
      union { uint4 q; u16 s[8]; } c8;
      c8.q = *(const uint4*)((const u16*)X + base);
      #pragma unroll
      for (int j = 0; j < 8; ++j) av[j] = b2f(c8.s[j]);
    }
    short8 ahi, alo;
    #pragma unroll
    for (int j = 0; j < 8; ++j){
      u16 hi, lo; split_bf16(av[j], hi, lo);
      ahi[j] = (short)hi; alo[j] = (short)lo;
    }
    #pragma unroll
    for (int c = 0; c < 4; ++c){
      uint4 wh = whi[(c*KS + ks)*64 + lane];
      uint4 wl = wlo[(c*KS + ks)*64 + lane];
      short8 bh = *(short8*)&wh;
      short8 bl = *(short8*)&wl;
      acc[c] = __builtin_amdgcn_mfma_f32_16x16x32_bf16(ahi, bh, acc[c], 0, 0, 0);
      acc[c] = __builtin_amdgcn_mfma_f32_16x16x32_bf16(ahi, bl, acc[c], 0, 0, 0);
      acc[c] = __builtin_amdgcn_mfma_f32_16x16x32_bf16(alo, bh, acc[c], 0, 0, 0);
    }
  }

  #pragma unroll
  for (int c = 0; c < 4; ++c){
    int col = c*16 + (lane & 15);
    float* dst = (col < 32) ? xl : xr;
    int kk = col & 31;
    #pragma unroll
    for (int r = 0; r < 4; ++r){
      int node = tile*16 + quad*4 + r;
      if (node < N_) dst[(size_t)node*D_HID + kk] = acc[c][r];
    }
  }
}

// ---------------- bucket count (LDS histogram, verified r8) ----------------
__global__ void bucket_count(const int* __restrict__ ei, const int* __restrict__ flags,
                             int* __restrict__ gcnt, int E_, int B_){
  __shared__ int hist[MAXB];
  for (int i = threadIdx.x; i < B_; i += 256) hist[i] = 0;
  __syncthreads();
  int chunk = (E_ + gridDim.x - 1) / gridDim.x;
  int s = blockIdx.x * chunk;
  int e = s + chunk; if (e > E_) e = E_;
  int is64 = flags[0];
  for (int i = s + (int)threadIdx.x; i < e; i += 256){
    int dst = is64 ? ei[2*E_ + 2*i] : ei[E_ + i];
    atomicAdd(&hist[dst >> BSH], 1);
  }
  __syncthreads();
  for (int i = threadIdx.x; i < B_; i += 256)
    if (hist[i]) (void)atomAddI(&gcnt[i], hist[i]);
}

// ---------------- exclusive scan over bucket counts (verified r8) ----------------
__global__ void scan_buckets(const int* __restrict__ gcnt, int* __restrict__ offsets,
                             int* __restrict__ cursor, int B_){
  __shared__ int sd[1024];
  int t = threadIdx.x;
  int v = (t < B_) ? gcnt[t] : 0;
  sd[t] = v;
  __syncthreads();
  for (int off = 1; off < 1024; off <<= 1){
    int tmp = (t >= off) ? sd[t-off] : 0;
    __syncthreads();
    sd[t] += tmp;
    __syncthreads();
  }
  if (t < B_){
    int excl = sd[t] - v;
    offsets[t] = excl;
    cursor[t]  = excl;
    if (t == B_-1) offsets[B_] = sd[t];
  }
}

// ---------------- bucket scatter with per-block range reservation (verified r8) ---
__global__ void bucket_scatter(const int* __restrict__ ei, const int* __restrict__ flags,
                               int* __restrict__ cursor, unsigned* __restrict__ seg,
                               int E_, int B_){
  __shared__ int hist[MAXB];
  __shared__ int bbase[MAXB];
  for (int i = threadIdx.x; i < B_; i += 256) hist[i] = 0;
  __syncthreads();
  int chunk = (E_ + gridDim.x - 1) / gridDim.x;
  int s = blockIdx.x * chunk;
  int e = s + chunk; if (e > E_) e = E_;
  int is64 = flags[0];
  for (int i = s + (int)threadIdx.x; i < e; i += 256){
    int dst = is64 ? ei[2*E_ + 2*i] : ei[E_ + i];
    atomicAdd(&hist[dst >> BSH], 1);
  }
  __syncthreads();
  for (int i = threadIdx.x; i < B_; i += 256){
    int c = hist[i];
    bbase[i] = c ? atomAddI(&cursor[i], c) : 0;
  }
  __syncthreads();
  for (int i = threadIdx.x; i < B_; i += 256) hist[i] = 0;  // reuse as local offset
  __syncthreads();
  for (int i = s + (int)threadIdx.x; i < e; i += 256){
    int src, dst;
    edge_nodes(ei, E_, is64, i, src, dst);
    int b = dst >> BSH;
    int pos = bbase[b] + atomicAdd(&hist[b], 1);
    seg[pos] = ((unsigned)src << BSH) | (unsigned)(dst & (BSZ-1));
  }
}

// ---------------- bucket finalize: exact per-dst CSR + degree histogram -----------
// csr stores the PACKED edge word (src<<7 | dst_local); gather derives the xl byte
// offset as (en & ~127u) == src*128. Also accumulates the global degree histogram
// (for the degree-sort) from the per-node counts it already has in LDS.
__global__ void bucket_finalize(const unsigned* __restrict__ seg,
                                const int* __restrict__ offsets,
                                int* __restrict__ row, int* __restrict__ csr_src,
                                int* __restrict__ dhist,
                                int N_, int B_){
  __shared__ int hist[BSZ];
  __shared__ int sc[BSZ];
  __shared__ int loff[BSZ];
  __shared__ int dh[MAXD];
  int b = blockIdx.x;
  int t = threadIdx.x;
  int base = offsets[b], cnt = offsets[b+1] - base;
  if (t < BSZ) hist[t] = 0;
  if (t < MAXD) dh[t] = 0;
  __syncthreads();
  for (int i = t; i < cnt; i += 256)
    atomicAdd(&hist[seg[base+i] & (BSZ-1)], 1);
  __syncthreads();
  if (t < BSZ){
    sc[t] = hist[t];
    int node = b*BSZ + t;
    if (node < N_) atomicAdd(&dh[min(hist[t], MAXD-1)], 1);
  }
  __syncthreads();
  for (int off = 1; off < BSZ; off <<= 1){
    int tmp = (t < BSZ && t >= off) ? sc[t-off] : 0;
    __syncthreads();
    if (t < BSZ) sc[t] += tmp;
    __syncthreads();
  }
  if (t < BSZ){
    int excl = sc[t] - hist[t];
    loff[t] = excl;
    int node = b*BSZ + t;
    if (node <= N_) row[node] = base + excl;
  }
  if (b == B_-1 && t == 0) row[N_] = offsets[B_];
  __syncthreads();
  for (int i = t; i < cnt; i += 256){
    unsigned en = seg[base+i];
    int dl = en & (BSZ-1);
    int pos = atomicAdd(&loff[dl], 1);
    csr_src[base + pos] = (int)en;          // packed: (src<<7)|dl
  }
  __syncthreads();
  if (t < MAXD && dh[t]) (void)atomAddI(&dhist[t], dh[t]);
}

// ---------------- degree-sort: scan + scatter (perm groups equal-degree nodes) ----
__global__ void scan_deg(const int* __restrict__ dhist, int* __restrict__ dcur){
  __shared__ int sd[MAXD];
  int t = threadIdx.x;
  int v = dhist[t];
  sd[t] = v;
  __syncthreads();
  for (int off = 1; off < MAXD; off <<= 1){
    int tmp = (t >= off) ? sd[t-off] : 0;
    __syncthreads();
    sd[t] += tmp;
    __syncthreads();
  }
  dcur[t] = sd[t] - v;
}

__global__ void deg_scatter(const int* __restrict__ row, int* __restrict__ dcur,
                            int* __restrict__ perm, int N_){
  __shared__ int h[MAXD];
  __shared__ int base[MAXD];
  int t = threadIdx.x;
  int chunk = (N_ + gridDim.x - 1) / gridDim.x;
  int s = blockIdx.x * chunk;
  int e = s + chunk; if (e > N_) e = N_;
  if (t < MAXD) h[t] = 0;
  __syncthreads();
  for (int n = s + t; n < e; n += 256){
    int d = min(row[n+1] - row[n], MAXD-1);
    atomicAdd(&h[d], 1);
  }
  __syncthreads();
  if (t < MAXD){
    int c = h[t];
    base[t] = c ? atomAddI(&dcur[t], c) : 0;
  }
  __syncthreads();
  if (t < MAXD) h[t] = 0;
  __syncthreads();
  for (int n = s + t; n < e; n += 256){
    int d = min(row[n+1] - row[n], MAXD-1);
    int pos = base[d] + atomicAdd(&h[d], 1);
    perm[pos] = n;
  }
}

// ---------------- group-per-node gather: 8 lanes per dst node, deep pipeline ------
// Wave = 8 dst nodes (one per 8-lane group), nodes degree-sorted via perm so the
// 8 groups have near-equal trip counts. 2 edges per iteration; xl prefetched 4
// edges ahead, csr 6 ahead, all with branchless clamped indices (min(i,last)).
// Dot reduce = 2 DPP quad-perm adds + 1 ds_swizzle. Arithmetic order identical
// to the sequential version (ev0 then ev1), so results are bit-identical.
__global__ void gat_gather(const int* __restrict__ row, const unsigned* __restrict__ csrp,
                           const int* __restrict__ perm,
                           const float* __restrict__ xl, const float* __restrict__ xr,
                           const void* __restrict__ att, const void* __restrict__ bias,
                           const int* __restrict__ flags,
                           float* __restrict__ outp, int N_, int do_relu)
{
  int G = (blockIdx.x * blockDim.x + threadIdx.x) >> 3;   // one node per 8-lane group
  if (G >= N_) return;
  int fl = threadIdx.x & 7;                               // feature block 0..7
  int f32 = flags[1];
  float4 attk;
  attk.x = ldf(att, f32, fl*4+0);
  attk.y = ldf(att, f32, fl*4+1);
  attk.z = ldf(att, f32, fl*4+2);
  attk.w = ldf(att, f32, fl*4+3);
  int n = perm[G];
  float4 xrk = *(const float4*)(xr + (size_t)n*D_HID + fl*4);
  int rs = row[n], re = row[n+1];
  const char* xlb = (const char*)xl;
  unsigned fo = (unsigned)(fl << 4);

  float4 acc = make_float4(0.f, 0.f, 0.f, 0.f);
  float ssum = 0.f;

  if (rs < re){
    int last = re - 1;
    unsigned c0 = csrp[rs];
    unsigned c1 = csrp[min(rs+1, last)];
    unsigned c2 = csrp[min(rs+2, last)];
    unsigned c3 = csrp[min(rs+3, last)];
    unsigned ca = csrp[min(rs+4, last)];
    unsigned cb = csrp[min(rs+5, last)];
    float4 xv0 = *(const float4*)(xlb + (c0 & ~127u) + fo);
    float4 xv1 = *(const float4*)(xlb + (c1 & ~127u) + fo);
    float4 xv2 = *(const float4*)(xlb + (c2 & ~127u) + fo);
    float4 xv3 = *(const float4*)(xlb + (c3 & ~127u) + fo);
    for (int i = rs; i < re; i += 2){
      // prefetch: xl for edges i+4, i+5; csr for edges i+6, i+7
      float4 nx0 = *(const float4*)(xlb + (ca & ~127u) + fo);
      float4 nx1 = *(const float4*)(xlb + (cb & ~127u) + fo);
      unsigned na = csrp[min(i+6, last)];
      unsigned nb = csrp[min(i+7, last)];
      // edge i (always valid)
      float ev0 = edge_ev(xv0, xrk, attk);
      ssum += ev0;
      acc.x = fmaf(ev0, xv0.x, acc.x);
      acc.y = fmaf(ev0, xv0.y, acc.y);
      acc.z = fmaf(ev0, xv0.z, acc.z);
      acc.w = fmaf(ev0, xv0.w, acc.w);
      // edge i+1 (masked on tail)
      float ev1 = edge_ev(xv1, xrk, attk);
      ev1 = (i + 1 <= last) ? ev1 : 0.f;
      ssum += ev1;
      acc.x = fmaf(ev1, xv1.x, acc.x);
      acc.y = fmaf(ev1, xv1.y, acc.y);
      acc.z = fmaf(ev1, xv1.z, acc.z);
      acc.w = fmaf(ev1, xv1.w, acc.w);
      // rotate pipeline
      xv0 = xv2; xv1 = xv3; xv2 = nx0; xv3 = nx1;
      ca = na; cb = nb;
    }
  }

  float inv = 1.0f / (ssum + 1e-16f);
  float4 o;
  o.x = acc.x*inv + ldf(bias, f32, fl*4+0);
  o.y = acc.y*inv + ldf(bias, f32, fl*4+1);
  o.z = acc.z*inv + ldf(bias, f32, fl*4+2);
  o.w = acc.w*inv + ldf(bias, f32, fl*4+3);
  if (do_relu){
    o.x = fmaxf(o.x, 0.f); o.y = fmaxf(o.y, 0.f);
    o.z = fmaxf(o.z, 0.f); o.w = fmaxf(o.w, 0.f);
  }
  *(float4*)(outp + (size_t)n*D_HID + fl*4) = o;
}

extern "C" void kernel_launch(void* const* d_in, const int* in_sizes, int n_in,
                              void* d_out, int out_size, void* d_ws, size_t ws_size,
                              hipStream_t stream)
{
  const void* x   = d_in[0];
  const int*  ei  = (const int*)d_in[1];
  const void* W1l = d_in[2];
  const void* W1r = d_in[3];
  const void* att1= d_in[4];
  const void* b1  = d_in[5];
  const void* W2l = d_in[6];
  const void* W2r = d_in[7];
  const void* att2= d_in[8];
  const void* b2  = d_in[9];
  float* out = (float*)d_out;

  int N_ = in_sizes[0] / D_IN;
  int E_ = in_sizes[1] / 2;
  int B_ = (N_ + BSZ - 1) / BSZ;

  char* ws = (char*)d_ws;
  size_t off = 0;
  auto carve = [&](size_t bytes) -> char* {
    char* p = ws + off;
    off += (bytes + 255) & ~(size_t)255;
    return p;
  };
  float*    xl      = (float*)   carve((size_t)N_ * D_HID * 4);
  float*    xr      = (float*)   carve((size_t)N_ * D_HID * 4);
  float*    h       = (float*)   carve((size_t)N_ * D_HID * 4);
  unsigned* seg     = (unsigned*)carve((size_t)E_ * 4);
  int*      csr_src = (int*)     carve((size_t)E_ * 4);
  int*      row     = (int*)     carve((size_t)(N_ + 1) * 4);
  int*      perm    = (int*)     carve((size_t)N_ * 4);
  int*      offsets = (int*)     carve((size_t)(MAXB + 1) * 4);
  int*      gcnt    = (int*)     carve((size_t)MAXB * 4);
  int*      cursor  = (int*)     carve((size_t)MAXB * 4);
  int*      dhist   = (int*)     carve((size_t)MAXD * 4);
  int*      dcur    = (int*)     carve((size_t)MAXD * 4);
  int*      flags   = (int*)     carve(256);
  uint4*    whi1    = (uint4*)   carve((size_t)4 * 4 * 64 * 16);  // K=128
  uint4*    wlo1    = (uint4*)   carve((size_t)4 * 4 * 64 * 16);
  uint4*    whi2    = (uint4*)   carve((size_t)4 * 1 * 64 * 16);  // K=32
  uint4*    wlo2    = (uint4*)   carve((size_t)4 * 1 * 64 * 16);

  const int tpb = 256;
  int gG = (N_ + 31) / 32;                  // group-per-node grid (32 nodes/block)
  int tiles = (N_ + 15) / 16;
  int gT = (tiles + 3) / 4;                 // mfma grid (4 waves/block)

  detect_flags<<<1, 256, 0, stream>>>(ei, (const u16*)x, flags);

  // ---- W fragments ----
  prep_wfrag<<<4, 256, 0, stream>>>(W1l, W1r, flags, D_IN, whi1, wlo1);
  prep_wfrag<<<1, 256, 0, stream>>>(W2l, W2r, flags, D_HID, whi2, wlo2);

  // ---- CSR build (shared by both layers) ----
  hipMemsetAsync(gcnt, 0, (size_t)MAXB * 4, stream);
  hipMemsetAsync(dhist, 0, (size_t)MAXD * 4, stream);
  bucket_count<<<256, tpb, 0, stream>>>(ei, flags, gcnt, E_, B_);
  scan_buckets<<<1, 1024, 0, stream>>>(gcnt, offsets, cursor, B_);
  bucket_scatter<<<256, tpb, 0, stream>>>(ei, flags, cursor, seg, E_, B_);
  bucket_finalize<<<B_, tpb, 0, stream>>>(seg, offsets, row, csr_src, dhist, N_, B_);

  // ---- degree sort (load-balances the gather waves) ----
  scan_deg<<<1, MAXD, 0, stream>>>(dhist, dcur);
  deg_scatter<<<64, tpb, 0, stream>>>(row, dcur, perm, N_);

  // ---- layer 1 ----
  mfma_gemm<D_IN><<<gT, tpb, 0, stream>>>(x, whi1, wlo1, flags, 0, xl, xr, N_);
  gat_gather<<<gG, tpb, 0, stream>>>(row, (const unsigned*)csr_src, perm, xl, xr,
                                     att1, b1, flags, h, N_, 1);

  // ---- layer 2 ----
  mfma_gemm<D_HID><<<gT, tpb, 0, stream>>>(h, whi2, wlo2, flags, 1, xl, xr, N_);
  gat_gather<<<gG, tpb, 0, stream>>>(row, (const unsigned*)csr_src, perm, xl, xr,
                                     att2, b2, flags, out, N_, 0);
}